// Round 3
// baseline (803.619 us; speedup 1.0000x reference)
//
#include <hip/hip_runtime.h>
#include <cstddef>

constexpr int HP  = 128 * 128;          // half-res pixels per channel
constexpr long long S = 8LL * 64 * HP;  // elements per (8,64,128,128) buffer

using short8 = __attribute__((ext_vector_type(8))) short;
using f32x4  = __attribute__((ext_vector_type(4))) float;

__device__ __forceinline__ unsigned short f2bf(float x) {
    union { float f; unsigned int u; } v{x};
    unsigned int r = v.u + 0x7FFFu + ((v.u >> 16) & 1u);  // RNE
    return (unsigned short)(r >> 16);
}
__device__ __forceinline__ float b2f(unsigned short u) {
    union { unsigned int i; float f; } v;
    v.i = ((unsigned int)u) << 16;
    return v.f;
}

// --------------------- DWT (Haar): ll planar fp32 + lh/hl/hh NHWC bf16 direct
__global__ __launch_bounds__(256) void k_dwt_fused(const float* __restrict__ x,
                                                   float* __restrict__ ll,
                                                   unsigned short* __restrict__ Tlh,
                                                   unsigned short* __restrict__ Thl,
                                                   unsigned short* __restrict__ Thh) {
    __shared__ unsigned short t3[3][64][66];
    int j0 = blockIdx.x * 64;
    int i  = blockIdx.y;
    int b  = blockIdx.z;
    int tid = threadIdx.x;
    int p = tid & 63, cg = tid >> 6;
#pragma unroll
    for (int k = 0; k < 16; ++k) {
        int c = cg * 16 + k;
        const float* xp = x + (((size_t)(b * 64 + c) * 256 + 2 * i) * 256 + 2 * (j0 + p));
        float2 top = *(const float2*)xp;
        float2 bot = *(const float2*)(xp + 256);
        float a = top.x, bb = top.y, cc = bot.x, d = bot.y;
        ll[((size_t)(b * 64 + c)) * HP + i * 128 + j0 + p] = (a + bb + cc + d) * 0.5f;
        t3[0][p][c] = f2bf((a - bb + cc - d) * 0.5f);
        t3[1][p][c] = f2bf((a + bb - cc - d) * 0.5f);
        t3[2][p][c] = f2bf((a - bb - cc + d) * 0.5f);
    }
    __syncthreads();
    int c = tid & 63, pg = tid >> 6;
    size_t rowbase = ((size_t)b * HP + (size_t)i * 128 + j0) * 64;
#pragma unroll
    for (int k = 0; k < 16; ++k) {
        int pp = pg * 16 + k;
        Tlh[rowbase + (size_t)pp * 64 + c] = t3[0][pp][c];
        Thl[rowbase + (size_t)pp * 64 + c] = t3[1][pp][c];
        Thh[rowbase + (size_t)pp * 64 + c] = t3[2][pp][c];
    }
}

// ---------------- weight reorder (oc,ic,3,3) fp32 -> [oc][s*64+ic] bf16
__global__ __launch_bounds__(256) void k_wreorder(const float* __restrict__ w,
                                                  unsigned short* __restrict__ wr, int total) {
    int idx = blockIdx.x * 256 + threadIdx.x;
    if (idx >= total) return;
    int oc = idx / 576, rem = idx - oc * 576;
    int s = rem >> 6, ic = rem & 63;
    wr[idx] = f2bf(w[(oc * 64 + ic) * 9 + s]);
}

// ---------------- grouped 3x3 conv (+ReLU) implicit-GEMM MFMA, bf16 in/out
#define ISTR 72
__global__ __launch_bounds__(256, 2) void k_conv3x3_mfma(
        const unsigned short* __restrict__ in,
        const unsigned short* __restrict__ wr,
        unsigned short* __restrict__ out, int out_ctot) {
    __shared__ __align__(16) unsigned short lin[324 * ISTR];  // 46656 B (reused as obuf)
    __shared__ __align__(16) unsigned short lw[64 * ISTR];    // 9216 B

    int tid = threadIdx.x;
    int b = blockIdx.y;
    int ty0 = (blockIdx.x >> 3) * 16, tx0 = (blockIdx.x & 7) * 16;

    // stage input halo tile (once)
    const unsigned short* inb = in + (size_t)b * HP * 64;
    for (int idx = tid; idx < 324 * 8; idx += 256) {
        int pr = idx >> 3, l8 = idx & 7;
        int py = pr / 18, px = pr - py * 18;
        int gy = ty0 + py - 1, gx = tx0 + px - 1;
        uint4 v = make_uint4(0, 0, 0, 0);
        if (gy >= 0 && gy < 128 && gx >= 0 && gx < 128)
            v = *(const uint4*)(inb + ((size_t)(gy * 128 + gx)) * 64 + l8 * 8);
        *(uint4*)&lin[pr * ISTR + l8 * 8] = v;
    }

    int wv = tid >> 6;
    int lane = tid & 63;
    int n16 = lane & 15, quad = lane >> 4;

    f32x4 acc[4][4];
#pragma unroll
    for (int mt = 0; mt < 4; ++mt)
#pragma unroll
        for (int nt = 0; nt < 4; ++nt) acc[mt][nt] = (f32x4){0.f, 0.f, 0.f, 0.f};

    // prefetch s=0 weights into registers
    int woc = tid >> 3, wl8 = (tid & 7) * 8;
    uint4 wA = *(const uint4*)(wr + woc * 576 + wl8);
    uint4 wB = *(const uint4*)(wr + (woc + 32) * 576 + wl8);

    for (int s = 0; s < 9; ++s) {
        __syncthreads();
        *(uint4*)&lw[woc * ISTR + wl8] = wA;
        *(uint4*)&lw[(woc + 32) * ISTR + wl8] = wB;
        if (s < 8) {  // prefetch next s (in flight during this s's MFMAs)
            wA = *(const uint4*)(wr + woc * 576 + (s + 1) * 64 + wl8);
            wB = *(const uint4*)(wr + (woc + 32) * 576 + (s + 1) * 64 + wl8);
        }
        __syncthreads();
        int sy = s / 3, sx = s - sy * 3;
#pragma unroll
        for (int half = 0; half < 2; ++half) {
            int ic0 = half * 32 + quad * 8;
            short8 a[4], bf[4];
#pragma unroll
            for (int mt = 0; mt < 4; ++mt)
                a[mt] = *(const short8*)&lw[(mt * 16 + n16) * ISTR + ic0];
#pragma unroll
            for (int nt = 0; nt < 4; ++nt) {
                int py = 4 * wv + nt + sy;
                int px = n16 + sx;
                bf[nt] = *(const short8*)&lin[(py * 18 + px) * ISTR + ic0];
            }
#pragma unroll
            for (int mt = 0; mt < 4; ++mt)
#pragma unroll
                for (int nt = 0; nt < 4; ++nt)
                    acc[mt][nt] = __builtin_amdgcn_mfma_f32_16x16x32_bf16(
                        a[mt], bf[nt], acc[mt][nt], 0, 0, 0);
        }
    }

    // epilogue: LDS transpose (obuf aliases lin) -> bf16 planar, vectorized
    float* obuf = (float*)lin;  // 16 oc x 260-stride fp32 = 16.6 KB
#pragma unroll 1
    for (int mt = 0; mt < 4; ++mt) {
        __syncthreads();
#pragma unroll
        for (int nt = 0; nt < 4; ++nt) {
            int row = 4 * wv + nt;
#pragma unroll
            for (int r = 0; r < 4; ++r)
                obuf[(quad * 4 + r) * 260 + row * 16 + n16] = acc[mt][nt][r];
        }
        __syncthreads();
#pragma unroll
        for (int k = 0; k < 4; ++k) {
            int ocl = (tid >> 6) * 4 + k;
            int px0 = (tid & 63) * 4;
            f32x4 vv = *(const f32x4*)&obuf[ocl * 260 + px0];
            unsigned int p0 = f2bf(fmaxf(vv[0], 0.f)) | ((unsigned int)f2bf(fmaxf(vv[1], 0.f)) << 16);
            unsigned int p1 = f2bf(fmaxf(vv[2], 0.f)) | ((unsigned int)f2bf(fmaxf(vv[3], 0.f)) << 16);
            int gy = ty0 + (px0 >> 4), gx = tx0 + (px0 & 15);
            *(uint2*)&out[((size_t)b * out_ctot + mt * 16 + ocl) * HP + (size_t)gy * 128 + gx] =
                make_uint2(p0, p1);
        }
    }
}

// ----------------------------------------------------- 1x1 conv, 64 out ch
__device__ __forceinline__ float ldval(const float* p) { return *p; }
__device__ __forceinline__ float ldval(const unsigned short* p) { return b2f(*p); }

template <int IC, bool RELU, typename TIN>
__global__ __launch_bounds__(256) void k_conv1x1(const TIN* __restrict__ in,
                                                 const float* __restrict__ w,
                                                 float* __restrict__ out) {
    __shared__ float wl[IC * 16];
    int tid = threadIdx.x;
    int occ = blockIdx.y, b = blockIdx.z;
    for (int idx = tid; idx < IC * 16; idx += 256) {
        int o = idx & 15, ic = idx >> 4;
        wl[idx] = w[(occ * 16 + o) * IC + ic];
    }
    __syncthreads();
    int p = blockIdx.x * 256 + tid;
    const TIN* inp = in + (size_t)b * IC * HP + p;
    float acc[16] = {};
    for (int ic = 0; ic < IC; ++ic) {
        float xv = ldval(inp + (size_t)ic * HP);
#pragma unroll
        for (int o = 0; o < 16; ++o) acc[o] += xv * wl[ic * 16 + o];
    }
    float* op = out + ((size_t)b * 64 + occ * 16) * HP + p;
#pragma unroll
    for (int o = 0; o < 16; ++o) op[o * HP] = RELU ? fmaxf(acc[o], 0.0f) : acc[o];
}

// ---------------- depthwise 3x3 (V slice) fused with v*(1+filt)
__global__ __launch_bounds__(256) void k_dwconv_v(const float* __restrict__ t,
                                                  const float* __restrict__ wdw,
                                                  const float* __restrict__ filt,
                                                  float* __restrict__ v) {
    long long idx = (long long)blockIdx.x * 256 + threadIdx.x;
    if (idx >= S) return;
    int j = (int)(idx & 127);
    int i = (int)((idx >> 7) & 127);
    int c = (int)((idx >> 14) & 63);
    long long bc = idx >> 14;
    const float* tp = t + bc * HP;
    const float* wp = wdw + c * 9;
    float acc = 0.0f;
#pragma unroll
    for (int ky = 0; ky < 3; ++ky) {
        int y = i + ky - 1;
        if (y < 0 || y >= 128) continue;
#pragma unroll
        for (int kx = 0; kx < 3; ++kx) {
            int x = j + kx - 1;
            if (x < 0 || x >= 128) continue;
            acc += tp[y * 128 + x] * wp[ky * 3 + kx];
        }
    }
    float f = filt[idx];
    v[idx] = acc * (1.0f + f);
}

// --------------- window attention (8x8) + fused proj 1x1, no-spill softmax
// scores bounded: |qn.qn|<=1, |bias|<~0.1, temp=1 -> exp safe without max-sub
__global__ __launch_bounds__(256) void k_attn_proj(const float* __restrict__ ll,
                                                   const float* __restrict__ v,
                                                   const float* __restrict__ table,
                                                   const float* __restrict__ temp,
                                                   const float* __restrict__ wproj,
                                                   float* __restrict__ outp) {
    __shared__ float qsT[64][68];   // [n][c]; reused as outC[c][68] after m-loop
    __shared__ float vsT[64][68];
    __shared__ float wlT[64][68];   // [ic][oc]
    __shared__ float tb[900];
    __shared__ float inv[4][64];
    int blk = blockIdx.x;
    int wj = blk & 15, wi = (blk >> 4) & 15, b = blk >> 8;
    int tid = threadIdx.x;

    for (int idx = tid; idx < 900; idx += 256) tb[idx] = table[idx];
    for (int idx = tid; idx < 4096; idx += 256) {
        int oc = idx & 63, c = idx >> 6;
        wlT[c][oc] = wproj[oc * 64 + c];
    }
    for (int idx = tid; idx < 4096; idx += 256) {
        int c = idx >> 6, n = idx & 63;
        int i = n >> 3, j = n & 7;
        int qy = (wi * 8 + i + 4) & 127, qx = (wj * 8 + j + 4) & 127;
        int vy = wi * 8 + i, vx = wj * 8 + j;
        size_t cb = ((size_t)b * 64 + c) * HP;
        qsT[n][c] = ll[cb + qy * 128 + qx];
        vsT[n][c] = v[cb + vy * 128 + vx];
    }
    __syncthreads();

    int h = tid >> 6, n = tid & 63;
    float q[16];
    float ss = 0.0f;
    {
        const float* qr = &qsT[n][h * 16];
#pragma unroll
        for (int d = 0; d < 16; ++d) { q[d] = qr[d]; ss += q[d] * q[d]; }
    }
    float invn = 1.0f / fmaxf(sqrtf(ss), 1e-12f);
#pragma unroll
    for (int d = 0; d < 16; ++d) q[d] *= invn;
    inv[h][n] = invn;
    __syncthreads();

    int i1 = n >> 3, j1 = n & 7;
    float tscale = temp[h];
    float sum = 0.0f;
    float acc[16] = {};
    for (int m = 0; m < 64; ++m) {
        const float* qm = &qsT[m][h * 16];
        float4 a0 = *(const float4*)(qm + 0), a1 = *(const float4*)(qm + 4);
        float4 a2 = *(const float4*)(qm + 8), a3 = *(const float4*)(qm + 12);
        float s = q[0] * a0.x + q[1] * a0.y + q[2] * a0.z + q[3] * a0.w
                + q[4] * a1.x + q[5] * a1.y + q[6] * a1.z + q[7] * a1.w
                + q[8] * a2.x + q[9] * a2.y + q[10] * a2.z + q[11] * a2.w
                + q[12] * a3.x + q[13] * a3.y + q[14] * a3.z + q[15] * a3.w;
        s *= inv[h][m];
        int i2 = m >> 3, j2 = m & 7;
        s = (s + tb[((i1 - i2 + 7) * 15 + (j1 - j2 + 7)) * 4 + h]) * tscale;
        float e = __expf(s);
        sum += e;
        const float* vm = &vsT[m][h * 16];
        float4 b0 = *(const float4*)(vm + 0), b1 = *(const float4*)(vm + 4);
        float4 b2 = *(const float4*)(vm + 8), b3 = *(const float4*)(vm + 12);
        acc[0] += e * b0.x;  acc[1] += e * b0.y;  acc[2] += e * b0.z;  acc[3] += e * b0.w;
        acc[4] += e * b1.x;  acc[5] += e * b1.y;  acc[6] += e * b1.z;  acc[7] += e * b1.w;
        acc[8] += e * b2.x;  acc[9] += e * b2.y;  acc[10] += e * b2.z; acc[11] += e * b2.w;
        acc[12] += e * b3.x; acc[13] += e * b3.y; acc[14] += e * b3.z; acc[15] += e * b3.w;
    }
    float rs = 1.0f / sum;
    __syncthreads();  // all reads of qsT done; reuse as outC[c][n]
#pragma unroll
    for (int d = 0; d < 16; ++d) qsT[h * 16 + d][n] = acc[d] * rs;
    __syncthreads();

    // proj: thread -> (px = tid&63, og = tid>>6), 16 oc each
    int px = tid & 63, og = tid >> 6;
    float accp[16] = {};
    for (int c = 0; c < 64; ++c) {
        float xv = qsT[c][px];
        const float* wr = &wlT[c][og * 16];
        float4 w0 = *(const float4*)(wr + 0), w1 = *(const float4*)(wr + 4);
        float4 w2 = *(const float4*)(wr + 8), w3 = *(const float4*)(wr + 12);
        accp[0] += xv * w0.x;  accp[1] += xv * w0.y;  accp[2] += xv * w0.z;  accp[3] += xv * w0.w;
        accp[4] += xv * w1.x;  accp[5] += xv * w1.y;  accp[6] += xv * w1.z;  accp[7] += xv * w1.w;
        accp[8] += xv * w2.x;  accp[9] += xv * w2.y;  accp[10] += xv * w2.z; accp[11] += xv * w2.w;
        accp[12] += xv * w3.x; accp[13] += xv * w3.y; accp[14] += xv * w3.z; accp[15] += xv * w3.w;
    }
    int ip = px >> 3, jp = px & 7;
    int oy = (wi * 8 + ip + 4) & 127, ox = (wj * 8 + jp + 4) & 127;
#pragma unroll
    for (int o = 0; o < 16; ++o)
        outp[((size_t)b * 64 + og * 16 + o) * HP + oy * 128 + ox] = accp[o];
}

// ---------------------------------------------------------------- IDWT (Haar)
__global__ __launch_bounds__(256) void k_idwt(const float* __restrict__ ll,
                                              const unsigned short* __restrict__ lh,
                                              const unsigned short* __restrict__ hl,
                                              const unsigned short* __restrict__ hh,
                                              float* __restrict__ out) {
    long long idx = (long long)blockIdx.x * 256 + threadIdx.x;
    if (idx >= S) return;
    int j = (int)(idx & 127);
    int i = (int)((idx >> 7) & 127);
    long long bc = idx >> 14;
    float L = ll[idx], A = b2f(lh[idx]), B = b2f(hl[idx]), D = b2f(hh[idx]);
    float a = (L + A + B + D) * 0.5f;
    float b = (L - A + B - D) * 0.5f;
    float c = (L + A - B - D) * 0.5f;
    float d = (L - A - B + D) * 0.5f;
    float* op = out + bc * 256 * 256;
    *(float2*)(op + (2 * i) * 256 + 2 * j) = make_float2(a, b);
    *(float2*)(op + (2 * i + 1) * 256 + 2 * j) = make_float2(c, d);
}

extern "C" void kernel_launch(void* const* d_in, const int* in_sizes, int n_in,
                              void* d_out, int out_size, void* d_ws, size_t ws_size,
                              hipStream_t stream) {
    const float* x        = (const float*)d_in[0];
    const float* temp     = (const float*)d_in[1];
    const float* table    = (const float*)d_in[2];
    const float* w_high1  = (const float*)d_in[3];  // (128,64,3,3)
    const float* w_high2  = (const float*)d_in[4];  // (64,128,1,1)
    const float* w_highout= (const float*)d_in[5];  // (192,64,3,3)
    const float* w_qkv    = (const float*)d_in[6];  // (192,64,1,1)
    const float* w_dwconv = (const float*)d_in[7];  // (192,1,3,3)
    const float* w_proj   = (const float*)d_in[8];  // (64,64,1,1)
    float* out = (float*)d_out;

    float* ws = (float*)d_ws;
    float* s0 = ws + 0 * S;  // ll fp32
    float* s1 = ws + 1 * S;  // filt1 bf16 (8,128,HP)
    float* s2 = ws + 2 * S;  // lh2 + hl2 bf16
    float* s3 = ws + 3 * S;  // hh2 bf16
    float* s4 = ws + 4 * S;  // T_lh | T_hl bf16
    float* s5 = ws + 5 * S;  // T_hh | reordered weights bf16
    float* s6 = ws + 6 * S;  // filt -> v fp32
    float* s7 = ws + 7 * S;  // t fp32
    float* s8 = ws + 8 * S;  // attn+proj out fp32

    unsigned short* T_lh = (unsigned short*)s4;
    unsigned short* T_hl = (unsigned short*)s4 + S;
    unsigned short* T_hh = (unsigned short*)s5;
    unsigned short* w_r1 = (unsigned short*)s5 + S;
    unsigned short* w_r2 = w_r1 + 128 * 576;
    unsigned short* u_f1 = (unsigned short*)s1;        // filt1 (8,128,HP) bf16
    unsigned short* u_lh2 = (unsigned short*)s2;
    unsigned short* u_hl2 = (unsigned short*)s2 + S;
    unsigned short* u_hh2 = (unsigned short*)s3;

    const int nblk = (int)(S / 256);
    dim3 b256(256);

    // 1. DWT: ll planar fp32 + high bands NHWC bf16
    dim3 dg(2, 128, 8);
    k_dwt_fused<<<dg, b256, 0, stream>>>(x, s0, T_lh, T_hl, T_hh);

    // 2. weight reorders
    k_wreorder<<<(128 * 576 + 255) / 256, b256, 0, stream>>>(w_high1, w_r1, 128 * 576);
    k_wreorder<<<(192 * 576 + 255) / 256, b256, 0, stream>>>(w_highout, w_r2, 192 * 576);

    // 3. filt1 = relu(conv3x3 g=2 on [lh,hl]) -> 128ch bf16 planar
    dim3 cg(64, 8);
    k_conv3x3_mfma<<<cg, b256, 0, stream>>>(T_lh, w_r1,            u_f1,            128);
    k_conv3x3_mfma<<<cg, b256, 0, stream>>>(T_hl, w_r1 + 64 * 576, u_f1 + 64 * HP,  128);

    // 4. filt = relu(1x1 128->64, bf16 in) -> s6
    dim3 g1(64, 4, 8);
    k_conv1x1<128, true><<<g1, b256, 0, stream>>>(u_f1, w_high2, s6);

    // 5. t = 1x1 of ll with V-rows of w_qkv -> s7
    k_conv1x1<64, false><<<g1, b256, 0, stream>>>(s0, w_qkv + 128 * 64, s7);

    // 6. v = dwconv3x3(t) * (1 + filt) -> s6
    k_dwconv_v<<<nblk, b256, 0, stream>>>(s7, w_dwconv + 128 * 9, s6, s6);

    // 7. window attention + fused proj -> s8
    k_attn_proj<<<2048, b256, 0, stream>>>(s0, s6, table, temp, w_proj, s8);

    // 8. high-frequency output branch: 3 grouped conv3x3 + relu (bf16 out)
    k_conv3x3_mfma<<<cg, b256, 0, stream>>>(T_lh, w_r2,             u_lh2, 64);
    k_conv3x3_mfma<<<cg, b256, 0, stream>>>(T_hl, w_r2 + 64 * 576,  u_hl2, 64);
    k_conv3x3_mfma<<<cg, b256, 0, stream>>>(T_hh, w_r2 + 128 * 576, u_hh2, 64);

    // 9. IDWT -> out
    k_idwt<<<nblk, b256, 0, stream>>>(s8, u_lh2, u_hl2, u_hh2, out);
}